// Round 15
// baseline (64.548 us; speedup 1.0000x reference)
//
#include <hip/hip_runtime.h>
#include <hip/hip_bf16.h>

#define NB 4
#define NL 1024
#define NH 16
#define ND 1024
#define HD 64
#define FMIN_F32 (-3.4028234663852886e38f)
#define LOG2E 1.4426950408889634f

typedef __bf16 bf16x8 __attribute__((ext_vector_type(8)));
typedef float f32x4 __attribute__((ext_vector_type(4)));
typedef unsigned int u32;

static __device__ inline unsigned short f2bf(float f) {
    __hip_bfloat16 h = __float2bfloat16(f);
    return __builtin_bit_cast(unsigned short, h);
}

// packed RNE f32x2 -> bf16x2 (low16 = bf16(a), high16 = bf16(b))
static __device__ __forceinline__ u32 cvtpk(float a, float b) {
    u32 r;
    asm("v_cvt_pk_bf16_f32 %0, %1, %2" : "=v"(r) : "v"(a), "v"(b));
    return r;
}

// pair split: (x,y) -> packed hi bf16x2 + packed lo bf16x2 (x ~= hi+lo)
static __device__ __forceinline__ void bfsplit2(float x, float y, u32& hiPk, u32& loPk) {
    hiPk = cvtpk(x, y);
    float hx = __builtin_bit_cast(float, hiPk << 16);
    float hy = __builtin_bit_cast(float, hiPk & 0xffff0000u);
    loPk = cvtpk(x - hx, y - hy);
}

// async global->LDS, 16B per lane. LDS dest = firstlane(lds)+lane*16.
static __device__ __forceinline__ void gload16(void* lds, const void* g) {
    __builtin_amdgcn_global_load_lds(
        (const __attribute__((address_space(1))) u32*)g,
        (__attribute__((address_space(3))) u32*)lds, 16, 0, 0);
}

// ---------------------------------------------------------------------------
// Kernel 1 (fused): rowsum of query/key/value  +  pre-swizzled transposes.
//  [0,3072):      rowsum of the three 16MB inputs
//  [3072,3328):   k_w -> kPhi/kPlo
//  [3328,3584):   v_w -> vP
//  [3584,3712):   o_w -> BP
// ---------------------------------------------------------------------------
__global__ __launch_bounds__(256)
void prep1_kernel(const float* __restrict__ query, const float* __restrict__ key,
                  const float* __restrict__ value,
                  const float* __restrict__ k_w, const float* __restrict__ v_w,
                  const float* __restrict__ o_w,
                  float* __restrict__ sums,
                  unsigned short* __restrict__ kPhi, unsigned short* __restrict__ kPlo,
                  unsigned short* __restrict__ vP, unsigned short* __restrict__ BP) {
    __shared__ float tile[64][132];
    const int tid = threadIdx.x;
    const int bx  = blockIdx.x;
    if (bx < 3072) {
        int gw   = bx * 4 + (tid >> 6);
        int lane = tid & 63;
        int tensor = gw >> 12;
        int row    = gw & 4095;
        const float* src = tensor == 0 ? query : (tensor == 1 ? key : value);
        const float* p = src + (size_t)row * ND;
        float s = 0.f;
#pragma unroll
        for (int t = 0; t < 4; ++t) {
            float4 x = *reinterpret_cast<const float4*>(p + t * 256 + lane * 4);
            s += (x.x + x.y) + (x.z + x.w);
        }
#pragma unroll
        for (int off = 32; off; off >>= 1) s += __shfl_xor(s, off);
        if (lane == 0) sums[tensor * (NB * NL) + row] = s;
    } else if (bx < 3328) {
        const int idx = bx - 3072;
        const int h = idx >> 4, jt = idx & 15;
        char* hiT = (char*)kPhi + (size_t)(h * 16 + jt) * 8192;
        char* loT = (char*)kPlo + (size_t)(h * 16 + jt) * 8192;
        const int row = tid >> 2;
        const int s0  = (tid & 3) * 16;
        const float* src = k_w + ((size_t)(h * NL + jt * 64 + row)) * HD + s0;
#pragma unroll
        for (int t = 0; t < 4; ++t) {
            float4 x = reinterpret_cast<const float4*>(src)[t];
            u32 h01, l01, h23, l23;
            bfsplit2(x.x, x.y, h01, l01);
            bfsplit2(x.z, x.w, h23, l23);
            int off = (row * 128 + (s0 + 4 * t) * 2) ^ ((row & 7) << 4);
            *(uint2*)(hiT + off) = make_uint2(h01, h23);
            *(uint2*)(loT + off) = make_uint2(l01, l23);
        }
    } else if (bx < 3584) {
        const int idx = bx - 3328;
        const int h = idx >> 4, jt = idx & 15;
#pragma unroll
        for (int t = 0; t < 4; ++t) {
            int id = tid + 256 * t;
            int j = id >> 4, t4 = (id & 15) * 4;
            *(float4*)&tile[j][t4] =
                *(const float4*)(v_w + ((size_t)(h * NL + jt * 64 + j)) * HD + t4);
        }
        __syncthreads();
        char* vT_ = (char*)vP + (size_t)(h * 16 + jt) * 8192;
        const int trow = tid >> 2;
        const int jq   = (tid & 3) * 16;
#pragma unroll
        for (int q2 = 0; q2 < 4; ++q2) {
            int j4 = jq + 4 * q2;
            uint2 u;
            u.x = cvtpk(tile[j4 + 0][trow], tile[j4 + 1][trow]);
            u.y = cvtpk(tile[j4 + 2][trow], tile[j4 + 3][trow]);
            int off = (trow * 128 + j4 * 2) ^ ((trow & 7) << 4);
            *(uint2*)(vT_ + off) = u;
        }
    } else {
        const int bxo = bx - 3584;
        const int ot = bxo >> 4, kt = bxo & 15;
#pragma unroll
        for (int t = 0; t < 8; ++t) {
            int id = tid + 256 * t;
            int c = id >> 5, o4 = (id & 31) * 4;
            *(float4*)&tile[c][o4] =
                *(const float4*)(o_w + ((size_t)(kt * 64 + c)) * ND + ot * 128 + o4);
        }
        __syncthreads();
        char* bT = (char*)BP + (size_t)(ot * 16 + kt) * 16384;
#pragma unroll
        for (int t = 0; t < 8; ++t) {
            int id = tid + 256 * t;
            int ol = id >> 4, c4 = (id & 15) * 4;
            uint2 u;
            u.x = cvtpk(tile[c4 + 0][ol], tile[c4 + 1][ol]);
            u.y = cvtpk(tile[c4 + 2][ol], tile[c4 + 3][ol]);
            int off = (ol * 128 + c4 * 2) ^ ((ol & 7) << 4);
            *(uint2*)(bT + off) = u;
        }
    }
}

// ---------------------------------------------------------------------------
// Kernel 2: sums-dependent prep — per-tile S sums + softmax tables.
// ---------------------------------------------------------------------------
__global__ __launch_bounds__(256)
void prep2_kernel(const float* __restrict__ v_w, const float* __restrict__ sums,
                  const int* __restrict__ pad, float* __restrict__ S,
                  float* __restrict__ ksm, float* __restrict__ vsm,
                  float* __restrict__ bsm) {
    __shared__ float tile[64][68];
    __shared__ float vsL[256];
    const int tid = threadIdx.x;
    const int bx  = blockIdx.x;
    const float* ksum = sums + NB * NL;
    const float* vsum = sums + 2 * NB * NL;
    if (bx < 256) {
        const int h = bx >> 4, jt = bx & 15;
        if (jt == 0) return;   // S[.,0,.] never read
#pragma unroll
        for (int t = 0; t < 4; ++t) {
            int id = tid + 256 * t;
            int j = id >> 4, t4 = (id & 15) * 4;
            *(float4*)&tile[j][t4] =
                *(const float4*)(v_w + ((size_t)(h * NL + jt * 64 + j)) * HD + t4);
        }
        vsL[tid] = vsum[(tid >> 6) * NL + jt * 64 + (tid & 63)];
        __syncthreads();
        const int b = tid >> 6, t = tid & 63;
        float a = 0.f;
#pragma unroll 16
        for (int j = 0; j < 64; ++j)
            a = fmaf(vsL[b * 64 + j], tile[j][t], a);
        S[(((size_t)h * 16 + jt) * 4 + b) * 64 + t] = a;
    } else {
        const int e = (bx - 256) * 256 + tid;   // 0..4095
        const int j = e >> 2, b = e & 3;
        const int pm = pad[b * NL + j];
        ksm[e] = pm ? 0.f : ksum[b * NL + j] * (LOG2E * 0.25f);
        vsm[e] = vsum[b * NL + j];
        bsm[e] = pm ? FMIN_F32 : 0.f;
    }
}

// ---------------------------------------------------------------------------
// Kernel 3: fused attn with causal-tile skip.
// Causal override hoisted under a wave-uniform (jt == cut-1) branch: for all
// earlier tiles max j < it0 <= i, so causal is provably false.
// ---------------------------------------------------------------------------
__global__ __launch_bounds__(512, 4)
void attn_kernel(const float* __restrict__ q_w, const float* __restrict__ sums,
                 const unsigned short* __restrict__ kPhi,
                 const unsigned short* __restrict__ kPlo,
                 const unsigned short* __restrict__ vP,
                 const float* __restrict__ ksm, const float* __restrict__ vsm,
                 const float* __restrict__ bsm, const float* __restrict__ S,
                 unsigned short* __restrict__ AP) {
    __shared__ __align__(16) unsigned short kHi[2][4096], kLo[2][4096], vTl[2][4096];
    __shared__ __align__(16) unsigned short qHi[2048], qLo[2048];
    __shared__ __align__(16) unsigned short wlds[8192];
    __shared__ __align__(16) float qs4[128];
    __shared__ __align__(16) float ks4[2][256];
    __shared__ __align__(16) float vs4[2][256];
    __shared__ __align__(16) float bs4[2][256];

    const float* qsum = sums;

    const int wid = blockIdx.x;
    const int gq  = wid >> 4;
    const int h   = wid & 15;
    const int itp = (gq < 16) ? (2 * gq) : (63 - 2 * gq);  // work-balanced remap
    const int it0 = itp * 32;
    const int cut = (it0 >> 6) + 1;
    const int cutm1 = cut - 1;

    const int tid  = threadIdx.x;
    const int lane = tid & 63;
    const int w    = tid >> 6;
    const int l15  = lane & 15;
    const int kb   = (lane >> 4) * 16;

    // ---- stage q tile (f32 -> bf16 hi/lo, swizzled), once ----
    {
        int row = tid >> 4;
        int s4  = (tid & 15) * 4;
        float4 x = *(const float4*)(q_w + ((size_t)(h * NL + it0 + row)) * HD + s4);
        u32 h01, l01, h23, l23;
        bfsplit2(x.x, x.y, h01, l01);
        bfsplit2(x.z, x.w, h23, l23);
        int off = (row * 128 + s4 * 2) ^ ((row & 7) << 4);
        *(uint2*)((char*)qHi + off) = make_uint2(h01, h23);
        *(uint2*)((char*)qLo + off) = make_uint2(l01, l23);
    }
    if (tid < 128) {
        int b = tid >> 5, i = tid & 31;
        qs4[i * 4 + b] = qsum[b * NL + it0 + i];
    }

    auto stage = [&](int buf, int jt) {
        const size_t tb = (size_t)(h * 16 + jt) * 8192 + tid * 16;
        gload16((char*)kHi[buf] + tid * 16, (const char*)kPhi + tb);
        gload16((char*)kLo[buf] + tid * 16, (const char*)kPlo + tb);
        gload16((char*)vTl[buf] + tid * 16, (const char*)vP + tb);
        if (w == 0)
            gload16((char*)ks4[buf] + lane * 16, (const char*)(ksm + jt * 256) + lane * 16);
        else if (w == 1)
            gload16((char*)vs4[buf] + lane * 16, (const char*)(vsm + jt * 256) + lane * 16);
        else if (w == 2)
            gload16((char*)bs4[buf] + lane * 16, (const char*)(bsm + jt * 256) + lane * 16);
    };

    const int gmi = (w & 1) * 16;     // i-frag base (B operand)
    const int gnj = (w >> 1) * 16;    // j-frag base (A operand)
    const int pb  = w >> 1;
    const int pmh = (w & 1) * 16;

    f32x4 accP[4];
#pragma unroll
    for (int n = 0; n < 4; ++n) accP[n] = (f32x4){0.f, 0.f, 0.f, 0.f};

    stage(0, 0);
    __syncthreads();
    int cur = 0;

    // per-thread softmax geometry (fixed i, 4 consecutive j per tile)
    const int i_sm  = gmi + l15;
    const int ig    = it0 + i_sm;
    const int jb_sm = gnj + (lane >> 4) * 4;
    const float4 qsv = *(const float4*)&qs4[i_sm * 4];
    const int woff = (i_sm * 128 + jb_sm * 2) ^ ((i_sm & 7) << 4);

    for (int jt = 0; jt < cut; ++jt) {
        const int j0 = jt * 64;
        if (jt + 1 < cut) stage(cur ^ 1, jt + 1);

        // ---- G: one 16x16 fragment per wave, bf16x3, split chains ----
        f32x4 gA = (f32x4){0.f, 0.f, 0.f, 0.f};
        f32x4 gB = (f32x4){0.f, 0.f, 0.f, 0.f};
#pragma unroll
        for (int ks = 0; ks < 2; ++ks) {
            const int arow = gnj + l15;   // K rows (A)
            const int brow = gmi + l15;   // Q rows (B)
            const int aoff = (arow * 128 + ks * 64 + kb) ^ ((arow & 7) << 4);
            const int boff = (brow * 128 + ks * 64 + kb) ^ ((brow & 7) << 4);
            bf16x8 kHiF = __builtin_bit_cast(bf16x8, *(const uint4*)((const char*)kHi[cur] + aoff));
            bf16x8 kLoF = __builtin_bit_cast(bf16x8, *(const uint4*)((const char*)kLo[cur] + aoff));
            bf16x8 qHiF = __builtin_bit_cast(bf16x8, *(const uint4*)((const char*)qHi + boff));
            bf16x8 qLoF = __builtin_bit_cast(bf16x8, *(const uint4*)((const char*)qLo + boff));
            gA = __builtin_amdgcn_mfma_f32_16x16x32_bf16(kHiF, qHiF, gA, 0, 0, 0);
            gA = __builtin_amdgcn_mfma_f32_16x16x32_bf16(kLoF, qHiF, gA, 0, 0, 0);
            gB = __builtin_amdgcn_mfma_f32_16x16x32_bf16(kHiF, qLoF, gB, 0, 0, 0);
        }
        const f32x4 g = gA + gB;

        // ---- per-lane 4-batch softmax (exp2 domain) ----
        {
            const bool lastTile = (jt == cutm1);   // wave-uniform
            float wv[4][4];   // [r][b]
#pragma unroll
            for (int r = 0; r < 4; ++r) {
                const int j  = jb_sm + r;
                const float4 ksv = *(const float4*)&ks4[cur][j * 4];
                const float4 vsv = *(const float4*)&vs4[cur][j * 4];
                const float4 bsv = *(const float4*)&bs4[cur][j * 4];
                const float gr = g[r];
                float sb0 = fmaf(qsv.x * ksv.x, gr, bsv.x);
                float sb1 = fmaf(qsv.y * ksv.y, gr, bsv.y);
                float sb2 = fmaf(qsv.z * ksv.z, gr, bsv.z);
                float sb3 = fmaf(qsv.w * ksv.w, gr, bsv.w);
                if (lastTile) {
                    // causal only possible in the final tile (j0+j > ig)
                    const bool causal = (j0 + j) > ig;
                    sb0 = causal ? 0.f : sb0;
                    sb1 = causal ? 0.f : sb1;
                    sb2 = causal ? 0.f : sb2;
                    sb3 = causal ? 0.f : sb3;
                }
                const float mx = fmaxf(fmaxf(sb0, sb1), fmaxf(sb2, sb3));
                const float e0 = __builtin_amdgcn_exp2f(sb0 - mx);
                const float e1 = __builtin_amdgcn_exp2f(sb1 - mx);
                const float e2 = __builtin_amdgcn_exp2f(sb2 - mx);
                const float e3 = __builtin_amdgcn_exp2f(sb3 - mx);
                const float inv = __builtin_amdgcn_rcpf((e0 + e1) + (e2 + e3));
                wv[r][0] = e0 * inv * vsv.x;
                wv[r][1] = e1 * inv * vsv.y;
                wv[r][2] = e2 * inv * vsv.z;
                wv[r][3] = e3 * inv * vsv.w;
            }
#pragma unroll
            for (int b = 0; b < 4; ++b) {
                uint2 p;
                p.x = cvtpk(wv[0][b], wv[1][b]);
                p.y = cvtpk(wv[2][b], wv[3][b]);
                *(uint2*)((char*)wlds + b * 4096 + woff) = p;
            }
        }
        // ---- barrier A: wlds visible; do NOT drain in-flight jt+1 stages ----
        asm volatile("s_waitcnt lgkmcnt(0)" ::: "memory");
        __builtin_amdgcn_s_barrier();
        __builtin_amdgcn_sched_barrier(0);

        // ---- PV: wave (pb, pmh): 16 i-rows x 64 t for batch pb ----
        __builtin_amdgcn_s_setprio(1);
#pragma unroll
        for (int ks = 0; ks < 2; ++ks) {
            const int arow = pmh + l15;
            const int aoff = pb * 4096 + ((arow * 128 + ks * 64 + kb) ^ ((arow & 7) << 4));
            bf16x8 aF = __builtin_bit_cast(bf16x8, *(const uint4*)((const char*)wlds + aoff));
#pragma unroll
            for (int n = 0; n < 4; ++n) {
                const int vrow = n * 16 + l15;
                const int voff = (vrow * 128 + ks * 64 + kb) ^ ((vrow & 7) << 4);
                bf16x8 bF = __builtin_bit_cast(bf16x8, *(const uint4*)((const char*)vTl[cur] + voff));
                accP[n] = __builtin_amdgcn_mfma_f32_16x16x32_bf16(aF, bF, accP[n], 0, 0, 0);
            }
        }
        __builtin_amdgcn_s_setprio(0);
        __syncthreads();   // full drain: stages landed, PV/wlds reads done
        cur ^= 1;
    }

    // ---- add fully-masked causal suffix: 0.25 * sum_{jt>=cut} S[h][jt][pb][t] ----
    if (cut < 16) {
        float sv[4] = {0.f, 0.f, 0.f, 0.f};
        for (int jt = cut; jt < 16; ++jt) {
            const float* sp = S + (((size_t)h * 16 + jt) * 4 + pb) * 64;
#pragma unroll
            for (int n = 0; n < 4; ++n) sv[n] += sp[n * 16 + l15];
        }
#pragma unroll
        for (int n = 0; n < 4; ++n) {
            const float s4v = 0.25f * sv[n];
#pragma unroll
            for (int r = 0; r < 4; ++r) accP[n][r] += s4v;
        }
    }

    // ---- store AP tiles (pre-swizzled out-GEMM A layout, bf16) ----
    {
        const int ib = (it0 + pmh) >> 4;
        char* tbase = (char*)AP + (size_t)((pb * 16 + h) * 16) * 8192;
#pragma unroll
        for (int n = 0; n < 4; ++n)
#pragma unroll
            for (int r = 0; r < 4; ++r) {
                int kt = (lane >> 4) * 4 + r;
                int tt = n * 16 + l15;
                int off = (ib * 128 + tt * 2) ^ ((ib & 7) << 4);
                *(unsigned short*)(tbase + (size_t)kt * 8192 + off) = f2bf(accP[n][r]);
            }
    }
}

// ---------------------------------------------------------------------------
// Kernel 4: out(4096x1024) = AP @ BP (unchanged).
// ---------------------------------------------------------------------------
__global__ __launch_bounds__(256, 2)
void outgemm_kernel(const unsigned short* __restrict__ AP,
                    const unsigned short* __restrict__ BP,
                    float* __restrict__ out) {
    __shared__ __align__(16) unsigned short aL[3][4096];
    __shared__ __align__(16) unsigned short bL[3][8192];
    const int ox = blockIdx.x;
    const int my = blockIdx.y;
    const int tid  = threadIdx.x;
    const int lane = tid & 63;
    const int w    = tid >> 6;
    const int wr = (w & 1) * 32;
    const int wc = (w >> 1) * 64;
    const int l15  = lane & 15;
    const int kseg = (lane >> 4) * 16;

    f32x4 acc[2][4];
#pragma unroll
    for (int m = 0; m < 2; ++m)
#pragma unroll
        for (int n = 0; n < 4; ++n) acc[m][n] = (f32x4){0.f, 0.f, 0.f, 0.f};

    auto stage = [&](int buf, int kt) {
        const char* at = (const char*)AP + (size_t)(my * 16 + kt) * 8192;
        const char* bt = (const char*)BP + (size_t)(ox * 16 + kt) * 16384;
        gload16((char*)aL[buf] + tid * 16, at + tid * 16);
        gload16((char*)aL[buf] + 4096 + tid * 16, at + 4096 + tid * 16);
#pragma unroll
        for (int r = 0; r < 4; ++r)
            gload16((char*)bL[buf] + r * 4096 + tid * 16, bt + r * 4096 + tid * 16);
    };

    auto compute = [&](int cb) {
        __builtin_amdgcn_s_setprio(1);
#pragma unroll
        for (int ks = 0; ks < 2; ++ks) {
            bf16x8 aF[2], bF[4];
#pragma unroll
            for (int m = 0; m < 2; ++m) {
                int row = wr + m * 16 + l15;
                int off = (row * 128 + ks * 64 + kseg) ^ ((row & 7) << 4);
                aF[m] = __builtin_bit_cast(bf16x8, *(const uint4*)((const char*)aL[cb] + off));
            }
#pragma unroll
            for (int n = 0; n < 4; ++n) {
                int row = wc + n * 16 + l15;
                int off = (row * 128 + ks * 64 + kseg) ^ ((row & 7) << 4);
                bF[n] = __builtin_bit_cast(bf16x8, *(const uint4*)((const char*)bL[cb] + off));
            }
#pragma unroll
            for (int m = 0; m < 2; ++m)
#pragma unroll
                for (int n = 0; n < 4; ++n)
                    acc[m][n] = __builtin_amdgcn_mfma_f32_16x16x32_bf16(
                        aF[m], bF[n], acc[m][n], 0, 0, 0);
        }
        __builtin_amdgcn_s_setprio(0);
    };

    stage(0, 0);
    stage(1, 1);
    for (int kt = 0; kt < 15; ++kt) {
        asm volatile("s_waitcnt vmcnt(6)" ::: "memory");
        __builtin_amdgcn_s_barrier();
        __builtin_amdgcn_sched_barrier(0);
        if (kt + 2 < 16) stage((kt + 2) % 3, kt + 2);
        compute(kt % 3);
    }
    asm volatile("s_waitcnt vmcnt(0)" ::: "memory");
    __builtin_amdgcn_s_barrier();
    __builtin_amdgcn_sched_barrier(0);
    compute(15 % 3);

#pragma unroll
    for (int m = 0; m < 2; ++m)
#pragma unroll
        for (int n = 0; n < 4; ++n)
#pragma unroll
            for (int r = 0; r < 4; ++r) {
                int row = my * 64 + wr + m * 16 + (lane >> 4) * 4 + r;
                int col = ox * 128 + wc + n * 16 + l15;
                out[(size_t)row * ND + col] = acc[m][n][r];
            }
}

// ---------------------------------------------------------------------------
extern "C" void kernel_launch(void* const* d_in, const int* in_sizes, int n_in,
                              void* d_out, int out_size, void* d_ws, size_t ws_size,
                              hipStream_t stream) {
    const float* query = (const float*)d_in[0];
    const float* key   = (const float*)d_in[1];
    const float* value = (const float*)d_in[2];
    const int*   pad   = (const int*)d_in[3];
    const float* q_w   = (const float*)d_in[4];
    const float* k_w   = (const float*)d_in[5];
    const float* v_w   = (const float*)d_in[6];
    const float* o_w   = (const float*)d_in[7];
    float* out = (float*)d_out;

    char* W = (char*)d_ws;
    float*          sums = (float*)W;                         // 48 KB
    unsigned short* kPhi = (unsigned short*)(W + 49152);      // 2 MB
    unsigned short* kPlo = (unsigned short*)(W + 2146304);    // 2 MB
    unsigned short* vP   = (unsigned short*)(W + 4243456);    // 2 MB
    unsigned short* BP   = (unsigned short*)(W + 6340608);    // 2 MB
    unsigned short* AP   = (unsigned short*)(W + 8437760);    // 8 MB
    float*          ksm  = (float*)(W + 16826368);            // 16 KB
    float*          vsm  = (float*)(W + 16842752);            // 16 KB
    float*          bsm  = (float*)(W + 16859136);            // 16 KB

    float* S = out;   // 256 KB scratch in d_out; overwritten by outgemm

    prep1_kernel<<<3712, 256, 0, stream>>>(query, key, value, k_w, v_w, o_w,
                                           sums, kPhi, kPlo, vP, BP);

    prep2_kernel<<<272, 256, 0, stream>>>(v_w, sums, pad, S, ksm, vsm, bsm);

    attn_kernel<<<512, 512, 0, stream>>>(q_w, sums, kPhi, kPlo, vP,
                                         ksm, vsm, bsm, S, AP);

    dim3 gg(8, 64);
    outgemm_kernel<<<gg, 256, 0, stream>>>(AP, BP, out);
}

// Round 16
// 63.114 us; speedup vs baseline: 1.0227x; 1.0227x over previous
//
#include <hip/hip_runtime.h>
#include <hip/hip_bf16.h>

#define NB 4
#define NL 1024
#define NH 16
#define ND 1024
#define HD 64
#define FMIN_F32 (-3.4028234663852886e38f)
#define LOG2E 1.4426950408889634f

typedef __bf16 bf16x8 __attribute__((ext_vector_type(8)));
typedef float f32x4 __attribute__((ext_vector_type(4)));
typedef unsigned int u32;

static __device__ inline unsigned short f2bf(float f) {
    __hip_bfloat16 h = __float2bfloat16(f);
    return __builtin_bit_cast(unsigned short, h);
}

// packed RNE f32x2 -> bf16x2 (low16 = bf16(a), high16 = bf16(b))
static __device__ __forceinline__ u32 cvtpk(float a, float b) {
    u32 r;
    asm("v_cvt_pk_bf16_f32 %0, %1, %2" : "=v"(r) : "v"(a), "v"(b));
    return r;
}

// pair split: (x,y) -> packed hi bf16x2 + packed lo bf16x2 (x ~= hi+lo)
static __device__ __forceinline__ void bfsplit2(float x, float y, u32& hiPk, u32& loPk) {
    hiPk = cvtpk(x, y);
    float hx = __builtin_bit_cast(float, hiPk << 16);
    float hy = __builtin_bit_cast(float, hiPk & 0xffff0000u);
    loPk = cvtpk(x - hx, y - hy);
}

// async global->LDS, 16B per lane. LDS dest = firstlane(lds)+lane*16.
static __device__ __forceinline__ void gload16(void* lds, const void* g) {
    __builtin_amdgcn_global_load_lds(
        (const __attribute__((address_space(1))) u32*)g,
        (__attribute__((address_space(3))) u32*)lds, 16, 0, 0);
}

// ---------------------------------------------------------------------------
// Kernel 1: row sums of query/key/value.
// ---------------------------------------------------------------------------
__global__ __launch_bounds__(256)
void rowsum_kernel(const float* __restrict__ q, const float* __restrict__ k,
                   const float* __restrict__ v, float* __restrict__ out) {
    int gw   = blockIdx.x * 4 + (threadIdx.x >> 6);
    int lane = threadIdx.x & 63;
    int tensor = gw >> 12;
    int row    = gw & 4095;
    const float* src = tensor == 0 ? q : (tensor == 1 ? k : v);
    const float* p = src + (size_t)row * ND;
    float s = 0.f;
#pragma unroll
    for (int t = 0; t < 4; ++t) {
        float4 x = *reinterpret_cast<const float4*>(p + t * 256 + lane * 4);
        s += (x.x + x.y) + (x.z + x.w);
    }
#pragma unroll
    for (int off = 32; off; off >>= 1) s += __shfl_xor(s, off);
    if (lane == 0) out[tensor * (NB * NL) + row] = s;
}

// ---------------------------------------------------------------------------
// Kernel 2: prep — pre-swizzled operand tiles + S sums + softmax tables (ws).
//  [0,256):   k_w -> kPhi/kPlo    [256,512): v_w -> vP + S
//  [512,640): o_w -> BP           [640,656): ksm/vsm/bsm tables (mask folded)
// ---------------------------------------------------------------------------
__global__ __launch_bounds__(256)
void prep_kernel(const float* __restrict__ k_w, const float* __restrict__ v_w,
                 const float* __restrict__ o_w, const float* __restrict__ sums,
                 const int* __restrict__ pad,
                 unsigned short* __restrict__ kPhi, unsigned short* __restrict__ kPlo,
                 unsigned short* __restrict__ vP, unsigned short* __restrict__ BP,
                 float* __restrict__ S, float* __restrict__ ksm,
                 float* __restrict__ vsm, float* __restrict__ bsm) {
    __shared__ float tile[64][132];
    __shared__ float vsL[256];
    const int tid = threadIdx.x;
    const int bx  = blockIdx.x;
    const float* ksum = sums + NB * NL;
    const float* vsum = sums + 2 * NB * NL;
    if (bx < 256) {
        const int h = bx >> 4, jt = bx & 15;
        char* hiT = (char*)kPhi + (size_t)(h * 16 + jt) * 8192;
        char* loT = (char*)kPlo + (size_t)(h * 16 + jt) * 8192;
        const int row = tid >> 2;
        const int s0  = (tid & 3) * 16;
        const float* src = k_w + ((size_t)(h * NL + jt * 64 + row)) * HD + s0;
#pragma unroll
        for (int t = 0; t < 4; ++t) {
            float4 x = reinterpret_cast<const float4*>(src)[t];
            u32 h01, l01, h23, l23;
            bfsplit2(x.x, x.y, h01, l01);
            bfsplit2(x.z, x.w, h23, l23);
            int off = (row * 128 + (s0 + 4 * t) * 2) ^ ((row & 7) << 4);
            *(uint2*)(hiT + off) = make_uint2(h01, h23);
            *(uint2*)(loT + off) = make_uint2(l01, l23);
        }
    } else if (bx < 512) {
        const int h = (bx - 256) >> 4, jt = (bx - 256) & 15;
#pragma unroll
        for (int t = 0; t < 4; ++t) {
            int id = tid + 256 * t;
            int j = id >> 4, t4 = (id & 15) * 4;
            *(float4*)&tile[j][t4] =
                *(const float4*)(v_w + ((size_t)(h * NL + jt * 64 + j)) * HD + t4);
        }
        vsL[tid] = vsum[(tid >> 6) * NL + jt * 64 + (tid & 63)];
        __syncthreads();
        char* vT_ = (char*)vP + (size_t)(h * 16 + jt) * 8192;
        const int trow = tid >> 2;
        const int jq   = (tid & 3) * 16;
#pragma unroll
        for (int q = 0; q < 4; ++q) {
            int j4 = jq + 4 * q;
            uint2 u;
            u.x = cvtpk(tile[j4 + 0][trow], tile[j4 + 1][trow]);
            u.y = cvtpk(tile[j4 + 2][trow], tile[j4 + 3][trow]);
            int off = (trow * 128 + j4 * 2) ^ ((trow & 7) << 4);
            *(uint2*)(vT_ + off) = u;
        }
        if (jt >= 1) {
            const int b = tid >> 6, t = tid & 63;
            float a = 0.f;
#pragma unroll 16
            for (int j = 0; j < 64; ++j)
                a = fmaf(vsL[b * 64 + j], tile[j][t], a);
            S[(((size_t)h * 16 + jt) * 4 + b) * 64 + t] = a;
        }
    } else if (bx < 640) {
        const int bxo = bx - 512;
        const int ot = bxo >> 4, kt = bxo & 15;
#pragma unroll
        for (int t = 0; t < 8; ++t) {
            int id = tid + 256 * t;
            int c = id >> 5, o4 = (id & 31) * 4;
            *(float4*)&tile[c][o4] =
                *(const float4*)(o_w + ((size_t)(kt * 64 + c)) * ND + ot * 128 + o4);
        }
        __syncthreads();
        char* bT = (char*)BP + (size_t)(ot * 16 + kt) * 16384;
#pragma unroll
        for (int t = 0; t < 8; ++t) {
            int id = tid + 256 * t;
            int ol = id >> 4, c4 = (id & 15) * 4;
            uint2 u;
            u.x = cvtpk(tile[c4 + 0][ol], tile[c4 + 1][ol]);
            u.y = cvtpk(tile[c4 + 2][ol], tile[c4 + 3][ol]);
            int off = (ol * 128 + c4 * 2) ^ ((ol & 7) << 4);
            *(uint2*)(bT + off) = u;
        }
    } else {
        // softmax tables with pad-mask folded in (layout: [j][b])
        const int e = (bx - 640) * 256 + tid;   // 0..4095
        const int j = e >> 2, b = e & 3;
        const int pm = pad[b * NL + j];
        ksm[e] = pm ? 0.f : ksum[b * NL + j] * (LOG2E * 0.25f);
        vsm[e] = vsum[b * NL + j];
        bsm[e] = pm ? FMIN_F32 : 0.f;
    }
}

// ---------------------------------------------------------------------------
// Kernel 3: fused attn with causal-tile skip (round-8 structure).
// Tables staged via gload16 (waves 0-2), draining at the tile-end barrier —
// no register round-trip, no mid-tile vmcnt stall.
// ---------------------------------------------------------------------------
__global__ __launch_bounds__(512, 4)
void attn_kernel(const float* __restrict__ q_w, const float* __restrict__ sums,
                 const unsigned short* __restrict__ kPhi,
                 const unsigned short* __restrict__ kPlo,
                 const unsigned short* __restrict__ vP,
                 const float* __restrict__ ksm, const float* __restrict__ vsm,
                 const float* __restrict__ bsm, const float* __restrict__ S,
                 unsigned short* __restrict__ AP) {
    __shared__ __align__(16) unsigned short kHi[2][4096], kLo[2][4096], vTl[2][4096];
    __shared__ __align__(16) unsigned short qHi[2048], qLo[2048];
    __shared__ __align__(16) unsigned short wlds[8192];
    __shared__ __align__(16) float qs4[128];
    __shared__ __align__(16) float ks4[2][256];
    __shared__ __align__(16) float vs4[2][256];
    __shared__ __align__(16) float bs4[2][256];

    const float* qsum = sums;

    const int wid = blockIdx.x;
    const int gq  = wid >> 4;
    const int h   = wid & 15;
    const int itp = (gq < 16) ? (2 * gq) : (63 - 2 * gq);  // work-balanced remap
    const int it0 = itp * 32;
    const int cut = (it0 >> 6) + 1;

    const int tid  = threadIdx.x;
    const int lane = tid & 63;
    const int w    = tid >> 6;
    const int l15  = lane & 15;
    const int kb   = (lane >> 4) * 16;

    // ---- stage q tile (f32 -> bf16 hi/lo, swizzled), once ----
    {
        int row = tid >> 4;
        int s4  = (tid & 15) * 4;
        float4 x = *(const float4*)(q_w + ((size_t)(h * NL + it0 + row)) * HD + s4);
        u32 h01, l01, h23, l23;
        bfsplit2(x.x, x.y, h01, l01);
        bfsplit2(x.z, x.w, h23, l23);
        int off = (row * 128 + s4 * 2) ^ ((row & 7) << 4);
        *(uint2*)((char*)qHi + off) = make_uint2(h01, h23);
        *(uint2*)((char*)qLo + off) = make_uint2(l01, l23);
    }
    if (tid < 128) {
        int b = tid >> 5, i = tid & 31;
        qs4[i * 4 + b] = qsum[b * NL + it0 + i];
    }

    auto stage = [&](int buf, int jt) {
        const size_t tb = (size_t)(h * 16 + jt) * 8192 + tid * 16;
        gload16((char*)kHi[buf] + tid * 16, (const char*)kPhi + tb);
        gload16((char*)kLo[buf] + tid * 16, (const char*)kPlo + tb);
        gload16((char*)vTl[buf] + tid * 16, (const char*)vP + tb);
        // tables: one wave each, 64 lanes x 16B = 1KB (256 floats) per table
        if (w == 0)
            gload16((char*)ks4[buf] + lane * 16, (const char*)(ksm + jt * 256) + lane * 16);
        else if (w == 1)
            gload16((char*)vs4[buf] + lane * 16, (const char*)(vsm + jt * 256) + lane * 16);
        else if (w == 2)
            gload16((char*)bs4[buf] + lane * 16, (const char*)(bsm + jt * 256) + lane * 16);
    };

    const int gmi = (w & 1) * 16;     // i-frag base (B operand)
    const int gnj = (w >> 1) * 16;    // j-frag base (A operand)
    const int pb  = w >> 1;
    const int pmh = (w & 1) * 16;

    f32x4 accP[4];
#pragma unroll
    for (int n = 0; n < 4; ++n) accP[n] = (f32x4){0.f, 0.f, 0.f, 0.f};

    stage(0, 0);
    __syncthreads();
    int cur = 0;

    // per-thread softmax geometry (fixed i, 4 consecutive j per tile)
    const int i_sm  = gmi + l15;
    const int ig    = it0 + i_sm;
    const int jb_sm = gnj + (lane >> 4) * 4;
    const float4 qsv = *(const float4*)&qs4[i_sm * 4];
    const int woff = (i_sm * 128 + jb_sm * 2) ^ ((i_sm & 7) << 4);

    for (int jt = 0; jt < cut; ++jt) {
        const int j0 = jt * 64;
        if (jt + 1 < cut) stage(cur ^ 1, jt + 1);

        // ---- G: one 16x16 fragment per wave, bf16x3, split chains ----
        f32x4 gA = (f32x4){0.f, 0.f, 0.f, 0.f};
        f32x4 gB = (f32x4){0.f, 0.f, 0.f, 0.f};
#pragma unroll
        for (int ks = 0; ks < 2; ++ks) {
            const int arow = gnj + l15;   // K rows (A)
            const int brow = gmi + l15;   // Q rows (B)
            const int aoff = (arow * 128 + ks * 64 + kb) ^ ((arow & 7) << 4);
            const int boff = (brow * 128 + ks * 64 + kb) ^ ((brow & 7) << 4);
            bf16x8 kHiF = __builtin_bit_cast(bf16x8, *(const uint4*)((const char*)kHi[cur] + aoff));
            bf16x8 kLoF = __builtin_bit_cast(bf16x8, *(const uint4*)((const char*)kLo[cur] + aoff));
            bf16x8 qHiF = __builtin_bit_cast(bf16x8, *(const uint4*)((const char*)qHi + boff));
            bf16x8 qLoF = __builtin_bit_cast(bf16x8, *(const uint4*)((const char*)qLo + boff));
            gA = __builtin_amdgcn_mfma_f32_16x16x32_bf16(kHiF, qHiF, gA, 0, 0, 0);
            gA = __builtin_amdgcn_mfma_f32_16x16x32_bf16(kLoF, qHiF, gA, 0, 0, 0);
            gB = __builtin_amdgcn_mfma_f32_16x16x32_bf16(kHiF, qLoF, gB, 0, 0, 0);
        }
        const f32x4 g = gA + gB;

        // ---- per-lane 4-batch softmax (exp2 domain) ----
        {
            float wv[4][4];   // [r][b]
#pragma unroll
            for (int r = 0; r < 4; ++r) {
                const int j  = jb_sm + r;
                const int jg = j0 + j;
                const float4 ksv = *(const float4*)&ks4[cur][j * 4];
                const float4 vsv = *(const float4*)&vs4[cur][j * 4];
                const float4 bsv = *(const float4*)&bs4[cur][j * 4];
                const float gr = g[r];
                const bool causal = jg > ig;
                float sb0 = fmaf(qsv.x * ksv.x, gr, bsv.x);
                float sb1 = fmaf(qsv.y * ksv.y, gr, bsv.y);
                float sb2 = fmaf(qsv.z * ksv.z, gr, bsv.z);
                float sb3 = fmaf(qsv.w * ksv.w, gr, bsv.w);
                sb0 = causal ? 0.f : sb0;
                sb1 = causal ? 0.f : sb1;
                sb2 = causal ? 0.f : sb2;
                sb3 = causal ? 0.f : sb3;
                const float mx = fmaxf(fmaxf(sb0, sb1), fmaxf(sb2, sb3));
                const float e0 = __builtin_amdgcn_exp2f(sb0 - mx);
                const float e1 = __builtin_amdgcn_exp2f(sb1 - mx);
                const float e2 = __builtin_amdgcn_exp2f(sb2 - mx);
                const float e3 = __builtin_amdgcn_exp2f(sb3 - mx);
                const float inv = __builtin_amdgcn_rcpf((e0 + e1) + (e2 + e3));
                wv[r][0] = e0 * inv * vsv.x;
                wv[r][1] = e1 * inv * vsv.y;
                wv[r][2] = e2 * inv * vsv.z;
                wv[r][3] = e3 * inv * vsv.w;
            }
#pragma unroll
            for (int b = 0; b < 4; ++b) {
                uint2 p;
                p.x = cvtpk(wv[0][b], wv[1][b]);
                p.y = cvtpk(wv[2][b], wv[3][b]);
                *(uint2*)((char*)wlds + b * 4096 + woff) = p;
            }
        }
        // ---- barrier A: wlds visible; do NOT drain in-flight jt+1 stages ----
        asm volatile("s_waitcnt lgkmcnt(0)" ::: "memory");
        __builtin_amdgcn_s_barrier();
        __builtin_amdgcn_sched_barrier(0);

        // ---- PV: wave (pb, pmh): 16 i-rows x 64 t for batch pb ----
        __builtin_amdgcn_s_setprio(1);
#pragma unroll
        for (int ks = 0; ks < 2; ++ks) {
            const int arow = pmh + l15;
            const int aoff = pb * 4096 + ((arow * 128 + ks * 64 + kb) ^ ((arow & 7) << 4));
            bf16x8 aF = __builtin_bit_cast(bf16x8, *(const uint4*)((const char*)wlds + aoff));
#pragma unroll
            for (int n = 0; n < 4; ++n) {
                const int vrow = n * 16 + l15;
                const int voff = (vrow * 128 + ks * 64 + kb) ^ ((vrow & 7) << 4);
                bf16x8 bF = __builtin_bit_cast(bf16x8, *(const uint4*)((const char*)vTl[cur] + voff));
                accP[n] = __builtin_amdgcn_mfma_f32_16x16x32_bf16(aF, bF, accP[n], 0, 0, 0);
            }
        }
        __builtin_amdgcn_s_setprio(0);
        __syncthreads();   // full drain: stages landed, PV/wlds reads done
        cur ^= 1;
    }

    // ---- add fully-masked causal suffix: 0.25 * sum_{jt>=cut} S[h][jt][pb][t] ----
    if (cut < 16) {
        float sv[4] = {0.f, 0.f, 0.f, 0.f};
        for (int jt = cut; jt < 16; ++jt) {
            const float* sp = S + (((size_t)h * 16 + jt) * 4 + pb) * 64;
#pragma unroll
            for (int n = 0; n < 4; ++n) sv[n] += sp[n * 16 + l15];
        }
#pragma unroll
        for (int n = 0; n < 4; ++n) {
            const float s4v = 0.25f * sv[n];
#pragma unroll
            for (int r = 0; r < 4; ++r) accP[n][r] += s4v;
        }
    }

    // ---- store AP tiles (pre-swizzled out-GEMM A layout, bf16) ----
    {
        const int ib = (it0 + pmh) >> 4;
        char* tbase = (char*)AP + (size_t)((pb * 16 + h) * 16) * 8192;
#pragma unroll
        for (int n = 0; n < 4; ++n)
#pragma unroll
            for (int r = 0; r < 4; ++r) {
                int kt = (lane >> 4) * 4 + r;
                int tt = n * 16 + l15;
                int off = (ib * 128 + tt * 2) ^ ((ib & 7) << 4);
                *(unsigned short*)(tbase + (size_t)kt * 8192 + off) = f2bf(accP[n][r]);
            }
    }
}

// ---------------------------------------------------------------------------
// Kernel 4: out(4096x1024) = AP @ BP. 64x128 tiles, grid (8,64), 256 threads.
// 3 LDS buffers, stage 2 ahead, counted vmcnt(6); setprio around MFMA.
// ---------------------------------------------------------------------------
__global__ __launch_bounds__(256, 2)
void outgemm_kernel(const unsigned short* __restrict__ AP,
                    const unsigned short* __restrict__ BP,
                    float* __restrict__ out) {
    __shared__ __align__(16) unsigned short aL[3][4096];
    __shared__ __align__(16) unsigned short bL[3][8192];
    const int ox = blockIdx.x;
    const int my = blockIdx.y;
    const int tid  = threadIdx.x;
    const int lane = tid & 63;
    const int w    = tid >> 6;
    const int wr = (w & 1) * 32;
    const int wc = (w >> 1) * 64;
    const int l15  = lane & 15;
    const int kseg = (lane >> 4) * 16;

    f32x4 acc[2][4];
#pragma unroll
    for (int m = 0; m < 2; ++m)
#pragma unroll
        for (int n = 0; n < 4; ++n) acc[m][n] = (f32x4){0.f, 0.f, 0.f, 0.f};

    auto stage = [&](int buf, int kt) {
        const char* at = (const char*)AP + (size_t)(my * 16 + kt) * 8192;
        const char* bt = (const char*)BP + (size_t)(ox * 16 + kt) * 16384;
        gload16((char*)aL[buf] + tid * 16, at + tid * 16);
        gload16((char*)aL[buf] + 4096 + tid * 16, at + 4096 + tid * 16);
#pragma unroll
        for (int r = 0; r < 4; ++r)
            gload16((char*)bL[buf] + r * 4096 + tid * 16, bt + r * 4096 + tid * 16);
    };

    auto compute = [&](int cb) {
        __builtin_amdgcn_s_setprio(1);
#pragma unroll
        for (int ks = 0; ks < 2; ++ks) {
            bf16x8 aF[2], bF[4];
#pragma unroll
            for (int m = 0; m < 2; ++m) {
                int row = wr + m * 16 + l15;
                int off = (row * 128 + ks * 64 + kseg) ^ ((row & 7) << 4);
                aF[m] = __builtin_bit_cast(bf16x8, *(const uint4*)((const char*)aL[cb] + off));
            }
#pragma unroll
            for (int n = 0; n < 4; ++n) {
                int row = wc + n * 16 + l15;
                int off = (row * 128 + ks * 64 + kseg) ^ ((row & 7) << 4);
                bF[n] = __builtin_bit_cast(bf16x8, *(const uint4*)((const char*)bL[cb] + off));
            }
#pragma unroll
            for (int m = 0; m < 2; ++m)
#pragma unroll
                for (int n = 0; n < 4; ++n)
                    acc[m][n] = __builtin_amdgcn_mfma_f32_16x16x32_bf16(
                        aF[m], bF[n], acc[m][n], 0, 0, 0);
        }
        __builtin_amdgcn_s_setprio(0);
    };

    stage(0, 0);
    stage(1, 1);
    for (int kt = 0; kt < 15; ++kt) {
        asm volatile("s_waitcnt vmcnt(6)" ::: "memory");
        __builtin_amdgcn_s_barrier();
        __builtin_amdgcn_sched_barrier(0);
        if (kt + 2 < 16) stage((kt + 2) % 3, kt + 2);
        compute(kt % 3);
    }
    asm volatile("s_waitcnt vmcnt(0)" ::: "memory");
    __builtin_amdgcn_s_barrier();
    __builtin_amdgcn_sched_barrier(0);
    compute(15 % 3);

#pragma unroll
    for (int m = 0; m < 2; ++m)
#pragma unroll
        for (int n = 0; n < 4; ++n)
#pragma unroll
            for (int r = 0; r < 4; ++r) {
                int row = my * 64 + wr + m * 16 + (lane >> 4) * 4 + r;
                int col = ox * 128 + wc + n * 16 + l15;
                out[(size_t)row * ND + col] = acc[m][n][r];
            }
}

// ---------------------------------------------------------------------------
extern "C" void kernel_launch(void* const* d_in, const int* in_sizes, int n_in,
                              void* d_out, int out_size, void* d_ws, size_t ws_size,
                              hipStream_t stream) {
    const float* query = (const float*)d_in[0];
    const float* key   = (const float*)d_in[1];
    const float* value = (const float*)d_in[2];
    const int*   pad   = (const int*)d_in[3];
    const float* q_w   = (const float*)d_in[4];
    const float* k_w   = (const float*)d_in[5];
    const float* v_w   = (const float*)d_in[6];
    const float* o_w   = (const float*)d_in[7];
    float* out = (float*)d_out;

    char* W = (char*)d_ws;
    float*          sums = (float*)W;                         // 48 KB
    unsigned short* kPhi = (unsigned short*)(W + 49152);      // 2 MB
    unsigned short* kPlo = (unsigned short*)(W + 2146304);    // 2 MB
    unsigned short* vP   = (unsigned short*)(W + 4243456);    // 2 MB
    unsigned short* BP   = (unsigned short*)(W + 6340608);    // 2 MB
    unsigned short* AP   = (unsigned short*)(W + 8437760);    // 8 MB
    float*          ksm  = (float*)(W + 16826368);            // 16 KB
    float*          vsm  = (float*)(W + 16842752);            // 16 KB
    float*          bsm  = (float*)(W + 16859136);            // 16 KB

    float* S = out;   // 256 KB scratch in d_out; overwritten by outgemm

    rowsum_kernel<<<3 * (NB * NL) / 4, 256, 0, stream>>>(query, key, value, sums);

    prep_kernel<<<656, 256, 0, stream>>>(k_w, v_w, o_w, sums, pad,
                                         kPhi, kPlo, vP, BP, S, ksm, vsm, bsm);

    attn_kernel<<<512, 512, 0, stream>>>(q_w, sums, kPhi, kPlo, vP,
                                         ksm, vsm, bsm, S, AP);

    dim3 gg(8, 64);
    outgemm_kernel<<<gg, 256, 0, stream>>>(AP, BP, out);
}